// Round 20
// baseline (250.459 us; speedup 1.0000x reference)
//
#include <hip/hip_runtime.h>
#include <math.h>

// Problem constants
#define NB    8192          // N
#define FEAT  255
#define HID   64
#define TOPK  6000
#define POSTK 300
#define BINS  8192          // 13-bit sortable-float key bins (sign+8exp+4mant)
#define BSHIFT 19           // 32-13
#define CAP   131072        // candidate buffer capacity
#define CAPLIM 49152        // target upper bound on estimated candidate count
#define SLACK 1             // bins below bstar (bf16-mfma vs f64 err 0.03 << bin 0.5)
#define TSEL  1000          // sampled cnt_ge target (1/8 col sample => true >= 6000 at +9.7 sigma)
#define JSLICES 128         // j-dimension parallelism for rank counting
#define LCAP  2048          // per-block LDS candidate buffer (overflow -> direct atomic)
#define NMS_ICH 64          // nms i-chunk per block

typedef __attribute__((ext_vector_type(8))) short bf16x8;
typedef __attribute__((ext_vector_type(4))) float f32x4;

__device__ __forceinline__ unsigned binOf(float x) {
    unsigned u = __float_as_uint(x);
    u = (u & 0x80000000u) ? ~u : (u | 0x80000000u);   // sortable key (ascending)
    return u >> BSHIFT;
}

__device__ __forceinline__ unsigned short f2bf(float f) {   // RNE bf16 (finite inputs)
    unsigned u = __float_as_uint(f);
    return (unsigned short)((u + 0x7fffu + ((u >> 16) & 1u)) >> 16);
}

// ---------------------------------------------------------------------------
// K0: one-time f32 -> f64 conversion of weights/biases (~33K elements).
// Removes per-iteration v_cvt from the mlp hot loop (R19: ~43% of mlp VALU
// slots were conversions).
// ---------------------------------------------------------------------------
__global__ __launch_bounds__(256) void cvt_w_kernel(
    const float* __restrict__ W1s, const float* __restrict__ W1o,
    const float* __restrict__ W2s, const float* __restrict__ W2o,
    const float* __restrict__ b1s, const float* __restrict__ b1o,
    const float* __restrict__ b2s, const float* __restrict__ b2o,
    double* __restrict__ W1s64, double* __restrict__ W1o64,
    double* __restrict__ W2s64, double* __restrict__ W2o64,
    double* __restrict__ b64)   // [0:64)=b1s [64:128)=b1o [128:192)=b2s [192:256)=b2o
{
    int idx = blockIdx.x * 256 + threadIdx.x;
    if (idx < FEAT * HID) { W1s64[idx] = (double)W1s[idx]; W1o64[idx] = (double)W1o[idx]; }
    if (idx < HID * HID)  { W2s64[idx] = (double)W2s[idx]; W2o64[idx] = (double)W2o[idx]; }
    if (idx < HID) {
        b64[idx]       = (double)b1s[idx];
        b64[idx + 64]  = (double)b1o[idx];
        b64[idx + 128] = (double)b2s[idx];
        b64[idx + 192] = (double)b2o[idx];
    }
}

// ---------------------------------------------------------------------------
// K1: the two 255->64->64 MLPs in f64, 4-way k-split, PURE-f64 hot loop:
// W pre-converted (K0), feat rows staged into LDS as f64 once per block.
// Accumulation order bit-identical to prior passing rounds (sequential k
// within quarter, deterministic 4-way LDS merge).
// ---------------------------------------------------------------------------
__global__ __launch_bounds__(256) void mlp_kernel(
    const float* __restrict__ feat,
    const double* __restrict__ W1s, const double* __restrict__ W1o,
    const double* __restrict__ W2s, const double* __restrict__ W2o,
    const double* __restrict__ b64,
    double* __restrict__ Xs64, double* __restrict__ Xo64,
    unsigned short* __restrict__ Xsb, unsigned short* __restrict__ Xob)
{
    int tid = threadIdx.x;
    int t   = tid & 63;           // hidden unit
    int w   = tid >> 6;           // wave = k-quarter 0..3
    int rbase = blockIdx.x * 4;

    __shared__ double fd[4][256];     // 8 KB: feat rows in f64
    __shared__ double pS[4][4][64];   // [quarter][row][unit] partials, subject
    __shared__ double pO[4][4][64];   // object
    __shared__ double hs[4][64];
    __shared__ double ho[4][64];

    // stage feat rows (coalesced, converted once)
#pragma unroll
    for (int r = 0; r < 4; ++r)
        for (int k = tid; k < FEAT; k += 256)
            fd[r][k] = (double)feat[(size_t)(rbase + r) * FEAT + k];
    __syncthreads();

    int kbeg = w * 64;
    int kend = kbeg + 64; if (kend > FEAT) kend = FEAT;
    double as[4] = {0, 0, 0, 0}, ao[4] = {0, 0, 0, 0};
#pragma unroll 4
    for (int k = kbeg; k < kend; ++k) {
        double ws = W1s[k * HID + t];
        double wo = W1o[k * HID + t];
        double g0 = fd[0][k], g1 = fd[1][k];
        double g2 = fd[2][k], g3 = fd[3][k];
        as[0] += g0 * ws; as[1] += g1 * ws; as[2] += g2 * ws; as[3] += g3 * ws;
        ao[0] += g0 * wo; ao[1] += g1 * wo; ao[2] += g2 * wo; ao[3] += g3 * wo;
    }
#pragma unroll
    for (int i = 0; i < 4; ++i) { pS[w][i][t] = as[i]; pO[w][i][t] = ao[i]; }
    __syncthreads();

    {
        double v = b64[t]      + ((pS[0][w][t] + pS[1][w][t]) + (pS[2][w][t] + pS[3][w][t]));
        double u = b64[64 + t] + ((pO[0][w][t] + pO[1][w][t]) + (pO[2][w][t] + pO[3][w][t]));
        hs[w][t] = v > 0.0 ? v : 0.0;
        ho[w][t] = u > 0.0 ? u : 0.0;
    }
    __syncthreads();

    int k2beg = w * 16, k2end = k2beg + 16;
    double xs[4] = {0, 0, 0, 0}, xo[4] = {0, 0, 0, 0};
#pragma unroll 4
    for (int k = k2beg; k < k2end; ++k) {
        double ws = W2s[k * HID + t];
        double wo = W2o[k * HID + t];
#pragma unroll
        for (int i = 0; i < 4; ++i) {
            xs[i] += hs[i][k] * ws;
            xo[i] += ho[i][k] * wo;
        }
    }
#pragma unroll
    for (int i = 0; i < 4; ++i) { pS[w][i][t] = xs[i]; pO[w][i][t] = xo[i]; }
    __syncthreads();

    {
        double v = b64[128 + t] + ((pS[0][w][t] + pS[1][w][t]) + (pS[2][w][t] + pS[3][w][t]));
        double u = b64[192 + t] + ((pO[0][w][t] + pO[1][w][t]) + (pO[2][w][t] + pO[3][w][t]));
        size_t o = (size_t)(rbase + w) * HID + t;
        Xs64[o] = v;
        Xo64[o] = u;
        Xsb[o] = f2bf((float)v);
        Xob[o] = f2bf((float)u);
    }
}

// ---------------------------------------------------------------------------
// K2: histogram pass over the 1/8 column sample (cols 0..1023). Positive
// values only (threshold certainly > 0). C/D: col=lane&15, row=quad*4+reg.
// ---------------------------------------------------------------------------
__global__ __launch_bounds__(256) void mfma_hist(
    const unsigned short* __restrict__ Xsb, const unsigned short* __restrict__ Xob,
    unsigned* __restrict__ ghist)
{
    __shared__ unsigned hist[BINS];   // 32 KB
    int tid = threadIdx.x;
    for (int i = tid; i < BINS; i += 256) hist[i] = 0u;
    __syncthreads();

    int lane = tid & 63;
    int wave = tid >> 6;
    int quad = lane >> 4;
    int l16  = lane & 15;
    int r0 = blockIdx.y * 128 + (wave >> 1) * 64;
    int c0 = blockIdx.x * 128 + (wave & 1) * 64;   // gridDim.x = 8

    f32x4 acc[4][4];
    bf16x8 afr[2][4], bfr[2][4];
#pragma unroll
    for (int kc = 0; kc < 2; ++kc)
#pragma unroll
        for (int t = 0; t < 4; ++t) {
            afr[kc][t] = *(const bf16x8*)(Xsb + (size_t)(r0 + t * 16 + l16) * HID + kc * 32 + quad * 8);
            bfr[kc][t] = *(const bf16x8*)(Xob + (size_t)(c0 + t * 16 + l16) * HID + kc * 32 + quad * 8);
        }
#pragma unroll
    for (int ti = 0; ti < 4; ++ti)
#pragma unroll
        for (int tj = 0; tj < 4; ++tj) acc[ti][tj] = (f32x4){0, 0, 0, 0};
#pragma unroll
    for (int kc = 0; kc < 2; ++kc)
#pragma unroll
        for (int ti = 0; ti < 4; ++ti)
#pragma unroll
            for (int tj = 0; tj < 4; ++tj)
                acc[ti][tj] = __builtin_amdgcn_mfma_f32_16x16x32_bf16(
                    afr[kc][ti], bfr[kc][tj], acc[ti][tj], 0, 0, 0);

#pragma unroll
    for (int ti = 0; ti < 4; ++ti)
#pragma unroll
        for (int tj = 0; tj < 4; ++tj)
#pragma unroll
            for (int i = 0; i < 4; ++i) {
                int r = r0 + ti * 16 + quad * 4 + i;
                int c = c0 + tj * 16 + l16;
                float v = acc[ti][tj][i];
                if (v > 0.0f && r != c)
                    atomicAdd(&hist[binOf(v)], 1u);
            }

    __syncthreads();
    for (int i = tid; i < BINS; i += 256) {
        unsigned h = hist[i];
        if (h) atomicAdd(&ghist[i], h);
    }
}

// ---------------------------------------------------------------------------
// K3: find bstar = largest bin with cnt_ge >= TSEL, lower by SLACK, walk up
// while the x8 estimate exceeds CAPLIM. Writes bin index (ctrl[1]) and
// FLOAT threshold (ctrl[2]) = lower edge of bin bt.
// ---------------------------------------------------------------------------
__global__ __launch_bounds__(256) void find_threshold(
    const unsigned* __restrict__ ghist, unsigned* __restrict__ ctrl)
{
    __shared__ unsigned csum[256];
    int tid  = threadIdx.x;
    int base = tid * (BINS / 256);
    unsigned s = 0;
    for (int i = 0; i < BINS / 256; ++i) s += ghist[base + i];
    csum[tid] = s;
    __syncthreads();
    if (tid == 0) {                       // suffix sums of chunk totals
        unsigned run = 0;
        for (int c = 255; c >= 0; --c) { run += csum[c]; csum[c] = run; }
    }
    __syncthreads();

    unsigned above = (tid == 255) ? 0u : csum[tid + 1];  // cnt_ge[chunk end]
    unsigned prev = above;
    for (int b = base + BINS / 256 - 1; b >= base; --b) {
        unsigned cur = prev + ghist[b];
        if (cur >= TSEL && prev < TSEL) {
            unsigned bstar = (unsigned)b;
            unsigned bt = bstar >= SLACK ? bstar - SLACK : 0;
            unsigned cnt = cur;
            for (unsigned bb = bstar; bb-- > bt;) cnt += ghist[bb];
            while (8u * cnt > CAPLIM && bt < bstar) { cnt -= ghist[bt]; bt++; }
            ctrl[1] = bt;
            unsigned key = bt << BSHIFT;
            unsigned fbits;
            if (key == 0u) fbits = 0xff800000u;               // -inf: all pass
            else fbits = (key & 0x80000000u) ? (key ^ 0x80000000u) : ~key;
            ctrl[2] = fbits;
            break;
        }
        prev = cur;
    }
}

// ---------------------------------------------------------------------------
// K4: filter pass, 128x256 tile/block, chunked 16-AGPR accumulator (R18's
// occupancy) + 1-deep B-fragment PREFETCH (R19's MLP): each chunk issues
// the next chunk's 2 B-loads before its MFMAs, overlapping load latency
// with compute/epilogue at only +16 VGPRs (~90 total -> ~5 waves/SIMD).
// Same candidate set; chunk order irrelevant.
// ---------------------------------------------------------------------------
__global__ __launch_bounds__(256) void mfma_filter(
    const unsigned short* __restrict__ Xsb, const unsigned short* __restrict__ Xob,
    unsigned* __restrict__ ctrl, unsigned* __restrict__ cidx)
{
    __shared__ unsigned lcnt;
    __shared__ unsigned gbase;
    __shared__ unsigned lbuf[LCAP];   // 8 KB
    float vt = __uint_as_float(ctrl[2]);
    int tid = threadIdx.x;
    if (tid == 0) lcnt = 0;

    int lane = tid & 63;
    int wave = tid >> 6;
    int quad = lane >> 4;
    int l16  = lane & 15;
    int r0 = blockIdx.y * 128 + (wave >> 1) * 64;
    int cb = blockIdx.x * 256 + (wave & 1) * 64;

    // A fragments: loaded once, reused across all 8 column chunks
    bf16x8 afr[2][4];
#pragma unroll
    for (int kc = 0; kc < 2; ++kc)
#pragma unroll
        for (int t = 0; t < 4; ++t)
            afr[kc][t] = *(const bf16x8*)(Xsb + (size_t)(r0 + t * 16 + l16) * HID + kc * 32 + quad * 8);

    // prefetch chunk 0's B fragments
    bf16x8 bcur[2];
    {
        int col = cb + l16;    // chunk 0: ct=0, tj=0
#pragma unroll
        for (int kc = 0; kc < 2; ++kc)
            bcur[kc] = *(const bf16x8*)(Xob + (size_t)col * HID + kc * 32 + quad * 8);
    }

    __syncthreads();   // lcnt=0 visible

#pragma unroll
    for (int q = 0; q < 8; ++q) {
        int ct = q >> 2, tj = q & 3;
        int c0 = cb + ct * 128;
        int cj = c0 + tj * 16 + l16;
        bool nodiag = (r0 != c0);

        // prefetch next chunk's B fragments (overlaps MFMAs + epilogue)
        bf16x8 bnext[2];
        if (q < 7) {
            int q2 = q + 1;
            int col2 = cb + (q2 >> 2) * 128 + (q2 & 3) * 16 + l16;
#pragma unroll
            for (int kc = 0; kc < 2; ++kc)
                bnext[kc] = *(const bf16x8*)(Xob + (size_t)col2 * HID + kc * 32 + quad * 8);
        }

        f32x4 acc[4];
#pragma unroll
        for (int ti = 0; ti < 4; ++ti) acc[ti] = (f32x4){0, 0, 0, 0};
#pragma unroll
        for (int kc = 0; kc < 2; ++kc)
#pragma unroll
            for (int ti = 0; ti < 4; ++ti)
                acc[ti] = __builtin_amdgcn_mfma_f32_16x16x32_bf16(
                    afr[kc][ti], bcur[kc], acc[ti], 0, 0, 0);

        if (nodiag) {
#pragma unroll
            for (int ti = 0; ti < 4; ++ti)
#pragma unroll
                for (int i = 0; i < 4; ++i) {
                    if (acc[ti][i] >= vt) {
                        int r = r0 + ti * 16 + quad * 4 + i;
                        unsigned rc = (unsigned)r * (unsigned)NB + (unsigned)cj;
                        unsigned p = atomicAdd(&lcnt, 1u);
                        if (p < LCAP) {
                            lbuf[p] = rc;
                        } else {
                            unsigned g = atomicAdd(&ctrl[0], 1u);
                            if (g < CAP) cidx[g] = rc;
                        }
                    }
                }
        } else {
#pragma unroll
            for (int ti = 0; ti < 4; ++ti)
#pragma unroll
                for (int i = 0; i < 4; ++i) {
                    int r = r0 + ti * 16 + quad * 4 + i;
                    if (acc[ti][i] >= vt && r != cj) {
                        unsigned rc = (unsigned)r * (unsigned)NB + (unsigned)cj;
                        unsigned p = atomicAdd(&lcnt, 1u);
                        if (p < LCAP) {
                            lbuf[p] = rc;
                        } else {
                            unsigned g = atomicAdd(&ctrl[0], 1u);
                            if (g < CAP) cidx[g] = rc;
                        }
                    }
                }
        }

        if (q < 7) { bcur[0] = bnext[0]; bcur[1] = bnext[1]; }
    }

    __syncthreads();
    unsigned n = lcnt; if (n > LCAP) n = LCAP;
    if (tid == 0 && n) gbase = atomicAdd(&ctrl[0], n);
    __syncthreads();
    for (unsigned i = tid; i < n; i += 256u) {
        unsigned p = gbase + i;
        if (p < CAP) cidx[p] = lbuf[i];
    }
}

// ---------------------------------------------------------------------------
// K4b: refine — one wave per candidate (grid-stride): 64 coalesced f64
// loads, product, butterfly reduce (deterministic; 1e-15 << 1e-5 gaps).
// ---------------------------------------------------------------------------
__global__ __launch_bounds__(256) void refine_kernel(
    const unsigned* __restrict__ ctrl, const unsigned* __restrict__ cidx,
    const double* __restrict__ Xs64, const double* __restrict__ Xo64,
    double* __restrict__ cval)
{
    unsigned M = ctrl[0];
    if (M > CAP) M = CAP;
    unsigned nw = gridDim.x * 4u;
    int lane = threadIdx.x & 63;
    for (unsigned w = blockIdx.x * 4u + (threadIdx.x >> 6); w < M; w += nw) {
        unsigned id = cidx[w];
        unsigned r = id >> 13, c = id & (NB - 1);
        double p = Xs64[(size_t)r * HID + lane] * Xo64[(size_t)c * HID + lane];
#pragma unroll
        for (int s = 32; s > 0; s >>= 1) p += __shfl_xor(p, s);
        if (lane == 0) cval[w] = (r == c) ? -1.0 : p;
    }
}

// ---------------------------------------------------------------------------
// K5a: rank-by-counting, 4 candidates per thread with stride-256 ownership
// inside a 1024-wide i-tile (coalesced loads/atomics). Inner loop reads
// each LDS (ev,ei) pair once for 4 composite compares. Key: value desc,
// index asc (jax top_k tie-break). Grid-stride i-tiles x j-slices.
// ---------------------------------------------------------------------------
__global__ __launch_bounds__(256) void rank_count(
    const unsigned* __restrict__ ctrl,
    const double* __restrict__ cval, const unsigned* __restrict__ cidx,
    unsigned* __restrict__ rank)
{
    unsigned M = ctrl[0];
    if (M > CAP) M = CAP;

    unsigned slice = blockIdx.y;
    unsigned jbeg = (unsigned)(((unsigned long long)slice * M) / JSLICES);
    unsigned jend = (unsigned)(((unsigned long long)(slice + 1) * M) / JSLICES);

    __shared__ double  lv[256];
    __shared__ unsigned li[256];

    for (unsigned itile = blockIdx.x; itile * 1024u < M; itile += gridDim.x) {
        unsigned i0 = itile * 1024u + threadIdx.x;   // + k*256 per slot
        double v[4];
        unsigned id[4];
        unsigned cnt[4] = {0, 0, 0, 0};
#pragma unroll
        for (int k = 0; k < 4; ++k) {
            unsigned idx = i0 + (unsigned)k * 256u;
            bool a = idx < M;
            v[k]  = a ? cval[idx] : 0.0;
            id[k] = a ? cidx[idx] : 0u;
        }

        for (unsigned base = jbeg; base < jend; base += 256u) {
            unsigned j = base + threadIdx.x;
            if (j < jend) { lv[threadIdx.x] = cval[j]; li[threadIdx.x] = cidx[j]; }
            __syncthreads();
            unsigned lim = jend - base; if (lim > 256u) lim = 256u;
            for (unsigned e = 0; e < lim; ++e) {
                double ev = lv[e];
                unsigned ei = li[e];
#pragma unroll
                for (int k = 0; k < 4; ++k)
                    cnt[k] += (ev > v[k]) || (ev == v[k] && ei < id[k]);
            }
            __syncthreads();
        }
#pragma unroll
        for (int k = 0; k < 4; ++k) {
            unsigned idx = i0 + (unsigned)k * 256u;
            if (idx < M && cnt[k]) atomicAdd(&rank[idx], cnt[k]);
        }
    }
}

// ---------------------------------------------------------------------------
// K5b: scatter rank<TOPK candidates into sorted arrays AND build the NMS
// union boxes + 0.7*area in the same pass.
// ---------------------------------------------------------------------------
__global__ __launch_bounds__(256) void rank_scatter_prep(
    const unsigned* __restrict__ ctrl,
    const double* __restrict__ cval, const unsigned* __restrict__ cidx,
    const unsigned* __restrict__ rank, const float* __restrict__ rois,
    double* __restrict__ sval, unsigned* __restrict__ sidx,
    double* __restrict__ ub)
{
    unsigned M = ctrl[0];
    if (M > CAP) M = CAP;
    unsigned stride = gridDim.x * 256u;
    for (unsigned t = blockIdx.x * 256u + threadIdx.x; t < M; t += stride) {
        unsigned rk = rank[t];
        if (rk < TOPK) {
            unsigned id = cidx[t];
            sval[rk] = cval[t];
            sidx[rk] = id;
            unsigned s = id >> 13, o = id & (NB - 1);
            const float* bs = rois + (size_t)s * 5;
            const float* bo = rois + (size_t)o * 5;
            double x1 = fmin((double)bs[1], (double)bo[1]);
            double y1 = fmin((double)bs[2], (double)bo[2]);
            double x2 = fmax((double)bs[3], (double)bo[3]);
            double y2 = fmax((double)bs[4], (double)bo[4]);
            double area = (x2 - x1) * (y2 - y1);
            double* u = ub + (size_t)rk * 5;
            u[0] = x1; u[1] = y1; u[2] = x2; u[3] = y2; u[4] = 0.7 * area;
        }
    }
}

// ---------------------------------------------------------------------------
// K7: suppressed[j] = OR_{i<j} (iou > 0.7), chunk-parallel & branchless.
// Block = 256 j's x 64-i chunk. Division-free test; plain store (benign).
// ---------------------------------------------------------------------------
__global__ __launch_bounds__(256) void nms_kernel(
    const double* __restrict__ ub, unsigned* sup)
{
    int jb = blockIdx.x;              // j-tile: 256 j's
    int ic = blockIdx.y;              // i-chunk: 64 i's
    int ibase = ic * NMS_ICH;
    if (ibase >= TOPK) return;
    if (ibase >= jb * 256 + 255) return;   // no i < j pairs in this block

    __shared__ double L[NMS_ICH][5];
    int tid = threadIdx.x;
    int icount = TOPK - ibase; if (icount > NMS_ICH) icount = NMS_ICH;
    for (int q = tid; q < icount * 5; q += 256)
        L[q / 5][q % 5] = ub[(size_t)ibase * 5 + q];
    __syncthreads();

    int j = jb * 256 + tid;
    if (j >= TOPK) return;
    int lim = j - ibase; if (lim > icount) lim = icount;  // i < j
    if (lim <= 0) return;

    const double* u = ub + (size_t)j * 5;
    double x1 = u[0], y1 = u[1], x2 = u[2], y2 = u[3], pa = u[4];
    bool flag = false;
    for (int e = 0; e < lim; ++e) {
        double ix1 = fmax(L[e][0], x1);
        double iy1 = fmax(L[e][1], y1);
        double ix2 = fmin(L[e][2], x2);
        double iy2 = fmin(L[e][3], y2);
        double iw = ix2 - ix1; iw = iw > 0.0 ? iw : 0.0;
        double ih = iy2 - iy1; ih = ih > 0.0 ? ih : 0.0;
        flag |= (1.7 * (iw * ih) > pa + L[e][4] + 7e-9);
    }
    if (flag) sup[j] = 1u;
}

// ---------------------------------------------------------------------------
// K8: top-300 of where(sup,-1,score) = stable partition of the sorted list.
// Ballot-based wave scans: 3 barriers/chunk.
// ---------------------------------------------------------------------------
__global__ __launch_bounds__(1024) void finalize_kernel(
    const unsigned* __restrict__ sup, const double* __restrict__ sval,
    const unsigned* __restrict__ sidx, float* __restrict__ out)
{
    __shared__ unsigned wsum[16];
    __shared__ unsigned red[16];
    __shared__ unsigned bases[2];   // running {unsup, sup} counts
    __shared__ unsigned totalu_s;
    int tid  = threadIdx.x;
    int lane = tid & 63;
    int w    = tid >> 6;

    unsigned s = 0;
    for (int i = tid; i < TOPK; i += 1024) s += (sup[i] == 0u);
#pragma unroll
    for (int st = 32; st > 0; st >>= 1) s += __shfl_down(s, st);
    if (lane == 0) red[w] = s;
    __syncthreads();
    if (tid == 0) {
        unsigned tot = 0;
        for (int i = 0; i < 16; ++i) tot += red[i];
        totalu_s = tot; bases[0] = 0; bases[1] = 0;
    }
    __syncthreads();
    unsigned totalu = totalu_s;

    for (int c = 0; c < (TOPK + 1023) / 1024; ++c) {
        int idx = c * 1024 + tid;
        int valid = TOPK - c * 1024; if (valid > 1024) valid = 1024;
        unsigned f = (idx < TOPK && sup[idx] == 0u) ? 1u : 0u;
        unsigned long long m = __ballot(f != 0u);
        if (lane == 0) wsum[w] = (unsigned)__popcll(m);
        __syncthreads();
        unsigned wbase = 0, ctot = 0;
        for (int i = 0; i < 16; ++i) {
            unsigned v = wsum[i];
            if (i < w) wbase += v;
            ctot += v;
        }
        unsigned e = wbase + (unsigned)__popcll(m & ((1ull << lane) - 1ull));
        if (idx < TOPK) {
            unsigned pos = f ? (bases[0] + e)
                             : (totalu + bases[1] + (unsigned)tid - e);
            if (pos < POSTK) {
                unsigned id = sidx[idx];
                unsigned sb = id >> 13, ob = id & (NB - 1);
                out[2 * pos]     = (float)sb;
                out[2 * pos + 1] = (float)ob;
                double sg = f ? 1.0 / (1.0 + exp(-sval[idx])) : -1.0;
                out[2 * POSTK + pos] = (float)sg;
            }
        }
        __syncthreads();
        if (tid == 0) {
            bases[0] += ctot;
            bases[1] += (unsigned)valid - ctot;
        }
        __syncthreads();
    }
}

// ---------------------------------------------------------------------------
extern "C" void kernel_launch(void* const* d_in, const int* in_sizes, int n_in,
                              void* d_out, int out_size, void* d_ws, size_t ws_size,
                              hipStream_t stream)
{
    const float* rois = (const float*)d_in[0];
    const float* feat = (const float*)d_in[1];
    const float* W1s  = (const float*)d_in[2];
    const float* b1s  = (const float*)d_in[3];
    const float* W2s  = (const float*)d_in[4];
    const float* b2s  = (const float*)d_in[5];
    const float* W1o  = (const float*)d_in[6];
    const float* b1o  = (const float*)d_in[7];
    const float* W2o  = (const float*)d_in[8];
    const float* b2o  = (const float*)d_in[9];

    char* ws = (char*)d_ws;
    size_t off = 0;
    auto alloc = [&](size_t bytes) -> void* {
        off = (off + 255) & ~(size_t)255;
        void* p = ws + off;
        off += bytes;
        return p;
    };

    // zeroed region first
    unsigned* ghist = (unsigned*)alloc((size_t)BINS * 4);     // histogram
    unsigned* ctrl  = (unsigned*)alloc(256);                  // [0]=count [1]=bin [2]=float thr
    unsigned* sup   = (unsigned*)alloc((size_t)6144 * 4);     // suppression flags
    unsigned* rank  = (unsigned*)alloc((size_t)CAP * 4);      // candidate ranks
    size_t zero_bytes = off;

    double* Xs64 = (double*)alloc((size_t)NB * HID * 8);
    double* Xo64 = (double*)alloc((size_t)NB * HID * 8);
    unsigned short* Xsb = (unsigned short*)alloc((size_t)NB * HID * 2);
    unsigned short* Xob = (unsigned short*)alloc((size_t)NB * HID * 2);
    double* cval = (double*)alloc((size_t)CAP * 8);
    unsigned* cidx = (unsigned*)alloc((size_t)CAP * 4);
    double* svalv = (double*)alloc((size_t)TOPK * 8);
    unsigned* sidxv = (unsigned*)alloc((size_t)TOPK * 4);
    double* ub   = (double*)alloc((size_t)TOPK * 5 * 8);
    double* W1s64 = (double*)alloc((size_t)FEAT * HID * 8);
    double* W1o64 = (double*)alloc((size_t)FEAT * HID * 8);
    double* W2s64 = (double*)alloc((size_t)HID * HID * 8);
    double* W2o64 = (double*)alloc((size_t)HID * HID * 8);
    double* b64   = (double*)alloc((size_t)256 * 8);

    hipMemsetAsync(d_ws, 0, zero_bytes, stream);

    cvt_w_kernel<<<(FEAT * HID + 255) / 256, 256, 0, stream>>>(
        W1s, W1o, W2s, W2o, b1s, b1o, b2s, b2o,
        W1s64, W1o64, W2s64, W2o64, b64);
    mlp_kernel<<<NB / 4, 256, 0, stream>>>(feat, W1s64, W1o64, W2s64, W2o64,
                                           b64, Xs64, Xo64, Xsb, Xob);
    mfma_hist<<<dim3(8, 64), 256, 0, stream>>>(Xsb, Xob, ghist);
    find_threshold<<<1, 256, 0, stream>>>(ghist, ctrl);
    mfma_filter<<<dim3(32, 64), 256, 0, stream>>>(Xsb, Xob, ctrl, cidx);
    refine_kernel<<<2048, 256, 0, stream>>>(ctrl, cidx, Xs64, Xo64, cval);
    rank_count<<<dim3(16, JSLICES), 256, 0, stream>>>(ctrl, cval, cidx, rank);
    rank_scatter_prep<<<512, 256, 0, stream>>>(ctrl, cval, cidx, rank, rois,
                                               svalv, sidxv, ub);
    nms_kernel<<<dim3((TOPK + 255) / 256, (TOPK + NMS_ICH - 1) / NMS_ICH), 256, 0, stream>>>(ub, sup);
    finalize_kernel<<<1, 1024, 0, stream>>>(sup, svalv, sidxv, (float*)d_out);
}

// Round 21
// 247.188 us; speedup vs baseline: 1.0132x; 1.0132x over previous
//
#include <hip/hip_runtime.h>
#include <math.h>

// Problem constants
#define NB    8192          // N
#define FEAT  255
#define HID   64
#define TOPK  6000
#define POSTK 300
#define BINS  8192          // 13-bit sortable-float key bins (sign+8exp+4mant)
#define BSHIFT 19           // 32-13
#define CAP   131072        // candidate buffer capacity
#define CAPLIM 49152        // target upper bound on estimated candidate count
#define SLACK 1             // bins below bstar (bf16-mfma vs f64 err 0.03 << bin 0.5)
#define TSEL  1000          // sampled cnt_ge target (1/8 col sample => true >= 6000 at +9.7 sigma)
#define JSLICES 128         // j-dimension parallelism for rank counting
#define LCAP  2048          // per-block LDS candidate buffer (overflow -> direct atomic)
#define NMS_ICH 64          // nms i-chunk per block

typedef __attribute__((ext_vector_type(8))) short bf16x8;
typedef __attribute__((ext_vector_type(4))) float f32x4;

__device__ __forceinline__ unsigned binOf(float x) {
    unsigned u = __float_as_uint(x);
    u = (u & 0x80000000u) ? ~u : (u | 0x80000000u);   // sortable key (ascending)
    return u >> BSHIFT;
}

__device__ __forceinline__ unsigned short f2bf(float f) {   // RNE bf16 (finite inputs)
    unsigned u = __float_as_uint(f);
    return (unsigned short)((u + 0x7fffu + ((u >> 16) & 1u)) >> 16);
}

// ---------------------------------------------------------------------------
// K1: the two 255->64->64 MLPs in f64, 4-way k-split (R19's measured-best
// variant: f32 W loads + inline cvt beat pre-converted f64 W, which doubled
// L2 W-traffic and cut occupancy — R20 post-mortem). Block = 4 rows, all 4
// waves on one row group, one k-quarter each; deterministic 4-way LDS merge
// (~1e-16 noise vs ~1e-5 rank gaps).
// ---------------------------------------------------------------------------
__global__ __launch_bounds__(256) void mlp_kernel(
    const float* __restrict__ feat,
    const float* __restrict__ W1s, const float* __restrict__ b1s,
    const float* __restrict__ W2s, const float* __restrict__ b2s,
    const float* __restrict__ W1o, const float* __restrict__ b1o,
    const float* __restrict__ W2o, const float* __restrict__ b2o,
    double* __restrict__ Xs64, double* __restrict__ Xo64,
    unsigned short* __restrict__ Xsb, unsigned short* __restrict__ Xob)
{
    int tid = threadIdx.x;
    int t   = tid & 63;           // hidden unit
    int w   = tid >> 6;           // wave = k-quarter 0..3
    int rbase = blockIdx.x * 4;

    __shared__ double pS[4][4][64];   // [quarter][row][unit] partials, subject
    __shared__ double pO[4][4][64];   // object
    __shared__ double hs[4][64];
    __shared__ double ho[4][64];

    const float* f0 = feat + (size_t)(rbase + 0) * FEAT;
    const float* f1 = feat + (size_t)(rbase + 1) * FEAT;
    const float* f2 = feat + (size_t)(rbase + 2) * FEAT;
    const float* f3 = feat + (size_t)(rbase + 3) * FEAT;

    int kbeg = w * 64;
    int kend = kbeg + 64; if (kend > FEAT) kend = FEAT;
    double as[4] = {0, 0, 0, 0}, ao[4] = {0, 0, 0, 0};
#pragma unroll 4
    for (int k = kbeg; k < kend; ++k) {
        double ws = (double)W1s[k * HID + t];
        double wo = (double)W1o[k * HID + t];
        double g0 = (double)f0[k], g1 = (double)f1[k];
        double g2 = (double)f2[k], g3 = (double)f3[k];
        as[0] += g0 * ws; as[1] += g1 * ws; as[2] += g2 * ws; as[3] += g3 * ws;
        ao[0] += g0 * wo; ao[1] += g1 * wo; ao[2] += g2 * wo; ao[3] += g3 * wo;
    }
#pragma unroll
    for (int i = 0; i < 4; ++i) { pS[w][i][t] = as[i]; pO[w][i][t] = ao[i]; }
    __syncthreads();

    {
        double v = (double)b1s[t] + ((pS[0][w][t] + pS[1][w][t]) + (pS[2][w][t] + pS[3][w][t]));
        double u = (double)b1o[t] + ((pO[0][w][t] + pO[1][w][t]) + (pO[2][w][t] + pO[3][w][t]));
        hs[w][t] = v > 0.0 ? v : 0.0;
        ho[w][t] = u > 0.0 ? u : 0.0;
    }
    __syncthreads();

    int k2beg = w * 16, k2end = k2beg + 16;
    double xs[4] = {0, 0, 0, 0}, xo[4] = {0, 0, 0, 0};
#pragma unroll 4
    for (int k = k2beg; k < k2end; ++k) {
        double ws = (double)W2s[k * HID + t];
        double wo = (double)W2o[k * HID + t];
#pragma unroll
        for (int i = 0; i < 4; ++i) {
            xs[i] += hs[i][k] * ws;
            xo[i] += ho[i][k] * wo;
        }
    }
#pragma unroll
    for (int i = 0; i < 4; ++i) { pS[w][i][t] = xs[i]; pO[w][i][t] = xo[i]; }
    __syncthreads();

    {
        double v = (double)b2s[t] + ((pS[0][w][t] + pS[1][w][t]) + (pS[2][w][t] + pS[3][w][t]));
        double u = (double)b2o[t] + ((pO[0][w][t] + pO[1][w][t]) + (pO[2][w][t] + pO[3][w][t]));
        size_t o = (size_t)(rbase + w) * HID + t;
        Xs64[o] = v;
        Xo64[o] = u;
        Xsb[o] = f2bf((float)v);
        Xob[o] = f2bf((float)u);
    }
}

// ---------------------------------------------------------------------------
// K2: histogram pass over the 1/8 column sample (cols 0..1023). Positive
// values only (threshold certainly > 0). C/D: col=lane&15, row=quad*4+reg.
// ---------------------------------------------------------------------------
__global__ __launch_bounds__(256) void mfma_hist(
    const unsigned short* __restrict__ Xsb, const unsigned short* __restrict__ Xob,
    unsigned* __restrict__ ghist)
{
    __shared__ unsigned hist[BINS];   // 32 KB
    int tid = threadIdx.x;
    for (int i = tid; i < BINS; i += 256) hist[i] = 0u;
    __syncthreads();

    int lane = tid & 63;
    int wave = tid >> 6;
    int quad = lane >> 4;
    int l16  = lane & 15;
    int r0 = blockIdx.y * 128 + (wave >> 1) * 64;
    int c0 = blockIdx.x * 128 + (wave & 1) * 64;   // gridDim.x = 8

    f32x4 acc[4][4];
    bf16x8 afr[2][4], bfr[2][4];
#pragma unroll
    for (int kc = 0; kc < 2; ++kc)
#pragma unroll
        for (int t = 0; t < 4; ++t) {
            afr[kc][t] = *(const bf16x8*)(Xsb + (size_t)(r0 + t * 16 + l16) * HID + kc * 32 + quad * 8);
            bfr[kc][t] = *(const bf16x8*)(Xob + (size_t)(c0 + t * 16 + l16) * HID + kc * 32 + quad * 8);
        }
#pragma unroll
    for (int ti = 0; ti < 4; ++ti)
#pragma unroll
        for (int tj = 0; tj < 4; ++tj) acc[ti][tj] = (f32x4){0, 0, 0, 0};
#pragma unroll
    for (int kc = 0; kc < 2; ++kc)
#pragma unroll
        for (int ti = 0; ti < 4; ++ti)
#pragma unroll
            for (int tj = 0; tj < 4; ++tj)
                acc[ti][tj] = __builtin_amdgcn_mfma_f32_16x16x32_bf16(
                    afr[kc][ti], bfr[kc][tj], acc[ti][tj], 0, 0, 0);

#pragma unroll
    for (int ti = 0; ti < 4; ++ti)
#pragma unroll
        for (int tj = 0; tj < 4; ++tj)
#pragma unroll
            for (int i = 0; i < 4; ++i) {
                int r = r0 + ti * 16 + quad * 4 + i;
                int c = c0 + tj * 16 + l16;
                float v = acc[ti][tj][i];
                if (v > 0.0f && r != c)
                    atomicAdd(&hist[binOf(v)], 1u);
            }

    __syncthreads();
    for (int i = tid; i < BINS; i += 256) {
        unsigned h = hist[i];
        if (h) atomicAdd(&ghist[i], h);
    }
}

// ---------------------------------------------------------------------------
// K3: find bstar = largest bin with cnt_ge >= TSEL, lower by SLACK, walk up
// while the x8 estimate exceeds CAPLIM. Writes bin index (ctrl[1]) and
// FLOAT threshold (ctrl[2]) = lower edge of bin bt.
// ---------------------------------------------------------------------------
__global__ __launch_bounds__(256) void find_threshold(
    const unsigned* __restrict__ ghist, unsigned* __restrict__ ctrl)
{
    __shared__ unsigned csum[256];
    int tid  = threadIdx.x;
    int base = tid * (BINS / 256);
    unsigned s = 0;
    for (int i = 0; i < BINS / 256; ++i) s += ghist[base + i];
    csum[tid] = s;
    __syncthreads();
    if (tid == 0) {                       // suffix sums of chunk totals
        unsigned run = 0;
        for (int c = 255; c >= 0; --c) { run += csum[c]; csum[c] = run; }
    }
    __syncthreads();

    unsigned above = (tid == 255) ? 0u : csum[tid + 1];  // cnt_ge[chunk end]
    unsigned prev = above;
    for (int b = base + BINS / 256 - 1; b >= base; --b) {
        unsigned cur = prev + ghist[b];
        if (cur >= TSEL && prev < TSEL) {
            unsigned bstar = (unsigned)b;
            unsigned bt = bstar >= SLACK ? bstar - SLACK : 0;
            unsigned cnt = cur;
            for (unsigned bb = bstar; bb-- > bt;) cnt += ghist[bb];
            while (8u * cnt > CAPLIM && bt < bstar) { cnt -= ghist[bt]; bt++; }
            ctrl[1] = bt;
            unsigned key = bt << BSHIFT;
            unsigned fbits;
            if (key == 0u) fbits = 0xff800000u;               // -inf: all pass
            else fbits = (key & 0x80000000u) ? (key ^ 0x80000000u) : ~key;
            ctrl[2] = fbits;
            break;
        }
        prev = cur;
    }
}

// ---------------------------------------------------------------------------
// K4: filter pass, 128x256 tile/block, chunked 16-AGPR accumulator (R18's
// occupancy) + 1-deep B-fragment prefetch (R19/R20's MLP): each chunk
// issues the next chunk's 2 B-loads before its MFMAs, overlapping load
// latency with compute/epilogue. Same candidate set; chunk order free.
// ---------------------------------------------------------------------------
__global__ __launch_bounds__(256) void mfma_filter(
    const unsigned short* __restrict__ Xsb, const unsigned short* __restrict__ Xob,
    unsigned* __restrict__ ctrl, unsigned* __restrict__ cidx)
{
    __shared__ unsigned lcnt;
    __shared__ unsigned gbase;
    __shared__ unsigned lbuf[LCAP];   // 8 KB
    float vt = __uint_as_float(ctrl[2]);
    int tid = threadIdx.x;
    if (tid == 0) lcnt = 0;

    int lane = tid & 63;
    int wave = tid >> 6;
    int quad = lane >> 4;
    int l16  = lane & 15;
    int r0 = blockIdx.y * 128 + (wave >> 1) * 64;
    int cb = blockIdx.x * 256 + (wave & 1) * 64;

    // A fragments: loaded once, reused across all 8 column chunks
    bf16x8 afr[2][4];
#pragma unroll
    for (int kc = 0; kc < 2; ++kc)
#pragma unroll
        for (int t = 0; t < 4; ++t)
            afr[kc][t] = *(const bf16x8*)(Xsb + (size_t)(r0 + t * 16 + l16) * HID + kc * 32 + quad * 8);

    // prefetch chunk 0's B fragments
    bf16x8 bcur[2];
    {
        int col = cb + l16;    // chunk 0: ct=0, tj=0
#pragma unroll
        for (int kc = 0; kc < 2; ++kc)
            bcur[kc] = *(const bf16x8*)(Xob + (size_t)col * HID + kc * 32 + quad * 8);
    }

    __syncthreads();   // lcnt=0 visible

#pragma unroll
    for (int q = 0; q < 8; ++q) {
        int ct = q >> 2, tj = q & 3;
        int c0 = cb + ct * 128;
        int cj = c0 + tj * 16 + l16;
        bool nodiag = (r0 != c0);

        // prefetch next chunk's B fragments (overlaps MFMAs + epilogue)
        bf16x8 bnext[2];
        if (q < 7) {
            int q2 = q + 1;
            int col2 = cb + (q2 >> 2) * 128 + (q2 & 3) * 16 + l16;
#pragma unroll
            for (int kc = 0; kc < 2; ++kc)
                bnext[kc] = *(const bf16x8*)(Xob + (size_t)col2 * HID + kc * 32 + quad * 8);
        }

        f32x4 acc[4];
#pragma unroll
        for (int ti = 0; ti < 4; ++ti) acc[ti] = (f32x4){0, 0, 0, 0};
#pragma unroll
        for (int kc = 0; kc < 2; ++kc)
#pragma unroll
            for (int ti = 0; ti < 4; ++ti)
                acc[ti] = __builtin_amdgcn_mfma_f32_16x16x32_bf16(
                    afr[kc][ti], bcur[kc], acc[ti], 0, 0, 0);

        if (nodiag) {
#pragma unroll
            for (int ti = 0; ti < 4; ++ti)
#pragma unroll
                for (int i = 0; i < 4; ++i) {
                    if (acc[ti][i] >= vt) {
                        int r = r0 + ti * 16 + quad * 4 + i;
                        unsigned rc = (unsigned)r * (unsigned)NB + (unsigned)cj;
                        unsigned p = atomicAdd(&lcnt, 1u);
                        if (p < LCAP) {
                            lbuf[p] = rc;
                        } else {
                            unsigned g = atomicAdd(&ctrl[0], 1u);
                            if (g < CAP) cidx[g] = rc;
                        }
                    }
                }
        } else {
#pragma unroll
            for (int ti = 0; ti < 4; ++ti)
#pragma unroll
                for (int i = 0; i < 4; ++i) {
                    int r = r0 + ti * 16 + quad * 4 + i;
                    if (acc[ti][i] >= vt && r != cj) {
                        unsigned rc = (unsigned)r * (unsigned)NB + (unsigned)cj;
                        unsigned p = atomicAdd(&lcnt, 1u);
                        if (p < LCAP) {
                            lbuf[p] = rc;
                        } else {
                            unsigned g = atomicAdd(&ctrl[0], 1u);
                            if (g < CAP) cidx[g] = rc;
                        }
                    }
                }
        }

        if (q < 7) { bcur[0] = bnext[0]; bcur[1] = bnext[1]; }
    }

    __syncthreads();
    unsigned n = lcnt; if (n > LCAP) n = LCAP;
    if (tid == 0 && n) gbase = atomicAdd(&ctrl[0], n);
    __syncthreads();
    for (unsigned i = tid; i < n; i += 256u) {
        unsigned p = gbase + i;
        if (p < CAP) cidx[p] = lbuf[i];
    }
}

// ---------------------------------------------------------------------------
// K4b: refine — one wave per candidate (grid-stride): 64 coalesced f64
// loads, product, butterfly reduce (deterministic; 1e-15 << 1e-5 gaps).
// ---------------------------------------------------------------------------
__global__ __launch_bounds__(256) void refine_kernel(
    const unsigned* __restrict__ ctrl, const unsigned* __restrict__ cidx,
    const double* __restrict__ Xs64, const double* __restrict__ Xo64,
    double* __restrict__ cval)
{
    unsigned M = ctrl[0];
    if (M > CAP) M = CAP;
    unsigned nw = gridDim.x * 4u;
    int lane = threadIdx.x & 63;
    for (unsigned w = blockIdx.x * 4u + (threadIdx.x >> 6); w < M; w += nw) {
        unsigned id = cidx[w];
        unsigned r = id >> 13, c = id & (NB - 1);
        double p = Xs64[(size_t)r * HID + lane] * Xo64[(size_t)c * HID + lane];
#pragma unroll
        for (int s = 32; s > 0; s >>= 1) p += __shfl_xor(p, s);
        if (lane == 0) cval[w] = (r == c) ? -1.0 : p;
    }
}

// ---------------------------------------------------------------------------
// K5a: rank-by-counting, 4 candidates per thread with stride-256 ownership
// inside a 1024-wide i-tile (coalesced loads/atomics). Inner loop reads
// each LDS (ev,ei) pair once for 4 composite compares. Key: value desc,
// index asc (jax top_k tie-break). Grid-stride i-tiles x j-slices.
// ---------------------------------------------------------------------------
__global__ __launch_bounds__(256) void rank_count(
    const unsigned* __restrict__ ctrl,
    const double* __restrict__ cval, const unsigned* __restrict__ cidx,
    unsigned* __restrict__ rank)
{
    unsigned M = ctrl[0];
    if (M > CAP) M = CAP;

    unsigned slice = blockIdx.y;
    unsigned jbeg = (unsigned)(((unsigned long long)slice * M) / JSLICES);
    unsigned jend = (unsigned)(((unsigned long long)(slice + 1) * M) / JSLICES);

    __shared__ double  lv[256];
    __shared__ unsigned li[256];

    for (unsigned itile = blockIdx.x; itile * 1024u < M; itile += gridDim.x) {
        unsigned i0 = itile * 1024u + threadIdx.x;   // + k*256 per slot
        double v[4];
        unsigned id[4];
        unsigned cnt[4] = {0, 0, 0, 0};
#pragma unroll
        for (int k = 0; k < 4; ++k) {
            unsigned idx = i0 + (unsigned)k * 256u;
            bool a = idx < M;
            v[k]  = a ? cval[idx] : 0.0;
            id[k] = a ? cidx[idx] : 0u;
        }

        for (unsigned base = jbeg; base < jend; base += 256u) {
            unsigned j = base + threadIdx.x;
            if (j < jend) { lv[threadIdx.x] = cval[j]; li[threadIdx.x] = cidx[j]; }
            __syncthreads();
            unsigned lim = jend - base; if (lim > 256u) lim = 256u;
            for (unsigned e = 0; e < lim; ++e) {
                double ev = lv[e];
                unsigned ei = li[e];
#pragma unroll
                for (int k = 0; k < 4; ++k)
                    cnt[k] += (ev > v[k]) || (ev == v[k] && ei < id[k]);
            }
            __syncthreads();
        }
#pragma unroll
        for (int k = 0; k < 4; ++k) {
            unsigned idx = i0 + (unsigned)k * 256u;
            if (idx < M && cnt[k]) atomicAdd(&rank[idx], cnt[k]);
        }
    }
}

// ---------------------------------------------------------------------------
// K5b: scatter rank<TOPK candidates into sorted arrays AND build the NMS
// union boxes + 0.7*area in the same pass.
// ---------------------------------------------------------------------------
__global__ __launch_bounds__(256) void rank_scatter_prep(
    const unsigned* __restrict__ ctrl,
    const double* __restrict__ cval, const unsigned* __restrict__ cidx,
    const unsigned* __restrict__ rank, const float* __restrict__ rois,
    double* __restrict__ sval, unsigned* __restrict__ sidx,
    double* __restrict__ ub)
{
    unsigned M = ctrl[0];
    if (M > CAP) M = CAP;
    unsigned stride = gridDim.x * 256u;
    for (unsigned t = blockIdx.x * 256u + threadIdx.x; t < M; t += stride) {
        unsigned rk = rank[t];
        if (rk < TOPK) {
            unsigned id = cidx[t];
            sval[rk] = cval[t];
            sidx[rk] = id;
            unsigned s = id >> 13, o = id & (NB - 1);
            const float* bs = rois + (size_t)s * 5;
            const float* bo = rois + (size_t)o * 5;
            double x1 = fmin((double)bs[1], (double)bo[1]);
            double y1 = fmin((double)bs[2], (double)bo[2]);
            double x2 = fmax((double)bs[3], (double)bo[3]);
            double y2 = fmax((double)bs[4], (double)bo[4]);
            double area = (x2 - x1) * (y2 - y1);
            double* u = ub + (size_t)rk * 5;
            u[0] = x1; u[1] = y1; u[2] = x2; u[3] = y2; u[4] = 0.7 * area;
        }
    }
}

// ---------------------------------------------------------------------------
// K7: suppressed[j] = OR_{i<j} (iou > 0.7), chunk-parallel & branchless.
// Block = 256 j's x 64-i chunk. Division-free test; plain store (benign).
// ---------------------------------------------------------------------------
__global__ __launch_bounds__(256) void nms_kernel(
    const double* __restrict__ ub, unsigned* sup)
{
    int jb = blockIdx.x;              // j-tile: 256 j's
    int ic = blockIdx.y;              // i-chunk: 64 i's
    int ibase = ic * NMS_ICH;
    if (ibase >= TOPK) return;
    if (ibase >= jb * 256 + 255) return;   // no i < j pairs in this block

    __shared__ double L[NMS_ICH][5];
    int tid = threadIdx.x;
    int icount = TOPK - ibase; if (icount > NMS_ICH) icount = NMS_ICH;
    for (int q = tid; q < icount * 5; q += 256)
        L[q / 5][q % 5] = ub[(size_t)ibase * 5 + q];
    __syncthreads();

    int j = jb * 256 + tid;
    if (j >= TOPK) return;
    int lim = j - ibase; if (lim > icount) lim = icount;  // i < j
    if (lim <= 0) return;

    const double* u = ub + (size_t)j * 5;
    double x1 = u[0], y1 = u[1], x2 = u[2], y2 = u[3], pa = u[4];
    bool flag = false;
    for (int e = 0; e < lim; ++e) {
        double ix1 = fmax(L[e][0], x1);
        double iy1 = fmax(L[e][1], y1);
        double ix2 = fmin(L[e][2], x2);
        double iy2 = fmin(L[e][3], y2);
        double iw = ix2 - ix1; iw = iw > 0.0 ? iw : 0.0;
        double ih = iy2 - iy1; ih = ih > 0.0 ? ih : 0.0;
        flag |= (1.7 * (iw * ih) > pa + L[e][4] + 7e-9);
    }
    if (flag) sup[j] = 1u;
}

// ---------------------------------------------------------------------------
// K8: top-300 of where(sup,-1,score) = stable partition of the sorted list.
// Ballot-based wave scans: 3 barriers/chunk.
// ---------------------------------------------------------------------------
__global__ __launch_bounds__(1024) void finalize_kernel(
    const unsigned* __restrict__ sup, const double* __restrict__ sval,
    const unsigned* __restrict__ sidx, float* __restrict__ out)
{
    __shared__ unsigned wsum[16];
    __shared__ unsigned red[16];
    __shared__ unsigned bases[2];   // running {unsup, sup} counts
    __shared__ unsigned totalu_s;
    int tid  = threadIdx.x;
    int lane = tid & 63;
    int w    = tid >> 6;

    unsigned s = 0;
    for (int i = tid; i < TOPK; i += 1024) s += (sup[i] == 0u);
#pragma unroll
    for (int st = 32; st > 0; st >>= 1) s += __shfl_down(s, st);
    if (lane == 0) red[w] = s;
    __syncthreads();
    if (tid == 0) {
        unsigned tot = 0;
        for (int i = 0; i < 16; ++i) tot += red[i];
        totalu_s = tot; bases[0] = 0; bases[1] = 0;
    }
    __syncthreads();
    unsigned totalu = totalu_s;

    for (int c = 0; c < (TOPK + 1023) / 1024; ++c) {
        int idx = c * 1024 + tid;
        int valid = TOPK - c * 1024; if (valid > 1024) valid = 1024;
        unsigned f = (idx < TOPK && sup[idx] == 0u) ? 1u : 0u;
        unsigned long long m = __ballot(f != 0u);
        if (lane == 0) wsum[w] = (unsigned)__popcll(m);
        __syncthreads();
        unsigned wbase = 0, ctot = 0;
        for (int i = 0; i < 16; ++i) {
            unsigned v = wsum[i];
            if (i < w) wbase += v;
            ctot += v;
        }
        unsigned e = wbase + (unsigned)__popcll(m & ((1ull << lane) - 1ull));
        if (idx < TOPK) {
            unsigned pos = f ? (bases[0] + e)
                             : (totalu + bases[1] + (unsigned)tid - e);
            if (pos < POSTK) {
                unsigned id = sidx[idx];
                unsigned sb = id >> 13, ob = id & (NB - 1);
                out[2 * pos]     = (float)sb;
                out[2 * pos + 1] = (float)ob;
                double sg = f ? 1.0 / (1.0 + exp(-sval[idx])) : -1.0;
                out[2 * POSTK + pos] = (float)sg;
            }
        }
        __syncthreads();
        if (tid == 0) {
            bases[0] += ctot;
            bases[1] += (unsigned)valid - ctot;
        }
        __syncthreads();
    }
}

// ---------------------------------------------------------------------------
extern "C" void kernel_launch(void* const* d_in, const int* in_sizes, int n_in,
                              void* d_out, int out_size, void* d_ws, size_t ws_size,
                              hipStream_t stream)
{
    const float* rois = (const float*)d_in[0];
    const float* feat = (const float*)d_in[1];
    const float* W1s  = (const float*)d_in[2];
    const float* b1s  = (const float*)d_in[3];
    const float* W2s  = (const float*)d_in[4];
    const float* b2s  = (const float*)d_in[5];
    const float* W1o  = (const float*)d_in[6];
    const float* b1o  = (const float*)d_in[7];
    const float* W2o  = (const float*)d_in[8];
    const float* b2o  = (const float*)d_in[9];

    char* ws = (char*)d_ws;
    size_t off = 0;
    auto alloc = [&](size_t bytes) -> void* {
        off = (off + 255) & ~(size_t)255;
        void* p = ws + off;
        off += bytes;
        return p;
    };

    // zeroed region first
    unsigned* ghist = (unsigned*)alloc((size_t)BINS * 4);     // histogram
    unsigned* ctrl  = (unsigned*)alloc(256);                  // [0]=count [1]=bin [2]=float thr
    unsigned* sup   = (unsigned*)alloc((size_t)6144 * 4);     // suppression flags
    unsigned* rank  = (unsigned*)alloc((size_t)CAP * 4);      // candidate ranks
    size_t zero_bytes = off;

    double* Xs64 = (double*)alloc((size_t)NB * HID * 8);
    double* Xo64 = (double*)alloc((size_t)NB * HID * 8);
    unsigned short* Xsb = (unsigned short*)alloc((size_t)NB * HID * 2);
    unsigned short* Xob = (unsigned short*)alloc((size_t)NB * HID * 2);
    double* cval = (double*)alloc((size_t)CAP * 8);
    unsigned* cidx = (unsigned*)alloc((size_t)CAP * 4);
    double* svalv = (double*)alloc((size_t)TOPK * 8);
    unsigned* sidxv = (unsigned*)alloc((size_t)TOPK * 4);
    double* ub   = (double*)alloc((size_t)TOPK * 5 * 8);

    hipMemsetAsync(d_ws, 0, zero_bytes, stream);

    mlp_kernel<<<NB / 4, 256, 0, stream>>>(feat, W1s, b1s, W2s, b2s,
                                           W1o, b1o, W2o, b2o,
                                           Xs64, Xo64, Xsb, Xob);
    mfma_hist<<<dim3(8, 64), 256, 0, stream>>>(Xsb, Xob, ghist);
    find_threshold<<<1, 256, 0, stream>>>(ghist, ctrl);
    mfma_filter<<<dim3(32, 64), 256, 0, stream>>>(Xsb, Xob, ctrl, cidx);
    refine_kernel<<<2048, 256, 0, stream>>>(ctrl, cidx, Xs64, Xo64, cval);
    rank_count<<<dim3(16, JSLICES), 256, 0, stream>>>(ctrl, cval, cidx, rank);
    rank_scatter_prep<<<512, 256, 0, stream>>>(ctrl, cval, cidx, rank, rois,
                                               svalv, sidxv, ub);
    nms_kernel<<<dim3((TOPK + 255) / 256, (TOPK + NMS_ICH - 1) / NMS_ICH), 256, 0, stream>>>(ub, sup);
    finalize_kernel<<<1, 1024, 0, stream>>>(sup, svalv, sidxv, (float*)d_out);
}